// Round 9
// baseline (89.585 us; speedup 1.0000x reference)
//
#include <hip/hip_runtime.h>

typedef _Float16 f16x8  __attribute__((ext_vector_type(8)));
typedef _Float16 f16x4  __attribute__((ext_vector_type(4)));
typedef __fp16   hf2    __attribute__((ext_vector_type(2)));
typedef float    f32x4  __attribute__((ext_vector_type(4)));
typedef float    f32x16 __attribute__((ext_vector_type(16)));

namespace {
constexpr int kN = 4, kL = 1024, kS = 1024, kH = 16, kE = 64, kD = 64;
constexpr int kRowF = kH * kE;     // 1024 floats: s-row stride of K and V
constexpr int KVB = 64;            // keys per LDS chunk
constexpr float SCL = 0.125f * 1.44269504088896340736f;  // 1/sqrt(E)*log2(e)

constexpr size_t kRows   = (size_t)kN * kL * kH;          // 65536 q-rows
constexpr size_t kOutFl  = kRows * kD;                    // 4,194,304 floats
constexpr size_t kPartFl = 2 * kOutFl;                    // two splits
constexpr size_t kMLFl   = 2 * kRows * 2;                 // (m,lsum) per split
constexpr size_t kWsNeed = (kPartFl + kMLFl) * sizeof(float);
}

__device__ __forceinline__ unsigned pku(float a, float b) {
  union { hf2 h; unsigned u; } u;
  u.h = __builtin_amdgcn_cvt_pkrtz(a, b);
  return u.u;
}
__device__ __forceinline__ f16x4 pk4(float a, float b, float c, float d) {
  union { hf2 h2[2]; f16x4 v; } u;
  u.h2[0] = __builtin_amdgcn_cvt_pkrtz(a, b);
  u.h2[1] = __builtin_amdgcn_cvt_pkrtz(c, d);
  return u.v;
}

// Round-6 verified structure: block = 4 waves x 32 q of one (n,h); KVB=64
// chunks in LDS f16, double-buffered, conflict-free XOR slot swizzles;
// 32x32x16 MFMA; swapped scores S^T = K.Q^T (C/D: col=lane&31=q,
// row=(reg&3)+8*(reg>>2)+4*(lane>>5)=s); P -> PV B-frag via cvt_pkrtz +
// permlane32_swap; defer-max THR=8; T14 stage scheduling.
// SPLIT=true: grid 1024, each block does one 512-key half of S and emits
// unnormalized acc + (m,lsum) to workspace (flash split-S decomposition).
// SPLIT=false: grid 512, single pass, writes O directly (round-6 fallback).
template <bool SPLIT>
__global__ __launch_bounds__(256, 2)
void attn_fwd_kernel(const float* __restrict__ Q, const float* __restrict__ K,
                     const float* __restrict__ V, const float* __restrict__ M,
                     const float* __restrict__ KLN, float* __restrict__ O,
                     float* __restrict__ PO, float* __restrict__ PML)
{
  __shared__ _Float16 Ks[2][KVB * 64];
  __shared__ _Float16 Vt[2][kD * 64];

  const int tid  = threadIdx.x;
  const int lane = tid & 63;
  const int wave = tid >> 6;      // 0..3
  const int l31  = lane & 31;     // q within wave-tile; also s/d row in frags
  const int hi   = lane >> 5;
  const int sr   = tid >> 4;      // staging row id 0..15
  const int sc4  = tid & 15;      // staging float4 column

  // XCD swizzle (grid % 8 == 0 -> bijective); all blocks of an (n,h) on one XCD
  int nh, qb, half;
  if (SPLIT) {
    const int swz = ((blockIdx.x & 7) << 7) | (blockIdx.x >> 3);
    half = swz & 1; qb = (swz >> 1) & 7; nh = swz >> 4;
  } else {
    const int swz = ((blockIdx.x & 7) << 6) | (blockIdx.x >> 3);
    half = 0; qb = swz & 7; nh = swz >> 3;
  }
  const int h = nh & (kH - 1), n = nh >> 4;
  const int qrow = qb * 128 + wave * 32 + l31;

  const float* Kp = K + ((size_t)n * kS * kH + h) * kE;
  const float* Vp = V + ((size_t)n * kS * kH + h) * kD;
  const float* Lp = KLN + (size_t)n * kS;
  const float* Mp = M + (size_t)qrow * kS;

  // ---- hoisted Q B-frags (pre-scaled): qf[ec], k = 16*ec + 8*hi + j ----
  f16x8 qf[4];
  {
    const float* Qp = Q + ((size_t)((size_t)n * kL + qrow) * kH + h) * kE;
    #pragma unroll
    for (int ec = 0; ec < 4; ++ec) {
      const f32x4 a = *reinterpret_cast<const f32x4*>(Qp + 16*ec + 8*hi);
      const f32x4 b = *reinterpret_cast<const f32x4*>(Qp + 16*ec + 8*hi + 4);
      union { f16x4 h4[2]; f16x8 v; } u;
      u.h4[0] = pk4(a[0]*SCL, a[1]*SCL, a[2]*SCL, a[3]*SCL);
      u.h4[1] = pk4(b[0]*SCL, b[1]*SCL, b[2]*SCL, b[3]*SCL);
      qf[ec] = u.v;
    }
  }

  // ---- per-thread LDS constants (verified round-6 math) ----
  const int kxor = (l31 & 7) << 1;
  int keyv[2], vrowb[2];
  #pragma unroll
  for (int dt = 0; dt < 2; ++dt) {
    const int d = 32*dt + l31;
    keyv[dt] = ((4*((d>>2)&3) + (d&3)) ^ (d>>2)) & 15;
    vrowb[dt] = d * 64;
  }
  int hwv[4];
  #pragma unroll
  for (int jd = 0; jd < 4; ++jd)
    hwv[jd] = ((4*(sc4 & 3) + jd) ^ sc4) & 15;

  const f32x16 z16 = {0,0,0,0, 0,0,0,0, 0,0,0,0, 0,0,0,0};
  f32x16 acc[2] = {z16, z16};
  float mrun = -1e30f, lsum = 0.f;

  constexpr int NC = SPLIT ? (kS / KVB / 2) : (kS / KVB);
  const int c0 = SPLIT ? half * NC : 0;

  // ---- staging helpers ----
  f32x4 ka[4], va[4];
  auto load_kv = [&](int sbase) {
    #pragma unroll
    for (int i = 0; i < 4; ++i)
      ka[i] = *reinterpret_cast<const f32x4*>(Kp + (size_t)(sbase + 16*i + sr) * kRowF + 4*sc4);
    #pragma unroll
    for (int js = 0; js < 4; ++js)
      va[js] = *reinterpret_cast<const f32x4*>(Vp + (size_t)(sbase + 4*sr + js) * kRowF + 4*sc4);
  };
  auto kv_write = [&](int buf) {
    #pragma unroll
    for (int i = 0; i < 4; ++i) {
      const int s = 16*i + sr;
      *reinterpret_cast<f16x4*>(&Ks[buf][s*64 + ((sc4 ^ ((s & 7) << 1)) << 2)]) =
          pk4(ka[i][0], ka[i][1], ka[i][2], ka[i][3]);
    }
    #pragma unroll
    for (int jd = 0; jd < 4; ++jd) {
      const int d = 4*sc4 + jd;
      *reinterpret_cast<f16x4*>(&Vt[buf][d*64 + ((sr ^ hwv[jd]) << 2)]) =
          pk4(va[0][jd], va[1][jd], va[2][jd], va[3][jd]);
    }
  };

  // ---- prologue ----
  load_kv(c0 * KVB);
  kv_write(0);
  load_kv((c0 + 1) * KVB);

  for (int c = 0; c < NC; ++c) {
    const int cur = c & 1;
    const int s0 = (c0 + c) * KVB;
    __syncthreads();
    if (c + 1 < NC) kv_write(cur ^ 1);           // chunk c+1 (loaded in body c-1)
    if (c + 2 < NC) load_kv((c0 + c + 2) * KVB); // consumed top of body c+1

    // mask / key_lengths prefetch (cover under QK)
    f32x4 mv[2][4], lv[2][4];
    #pragma unroll
    for (int st = 0; st < 2; ++st)
      #pragma unroll
      for (int m = 0; m < 4; ++m) {
        mv[st][m] = *reinterpret_cast<const f32x4*>(Mp + s0 + 32*st + 8*m + 4*hi);
        lv[st][m] = *reinterpret_cast<const f32x4*>(Lp + s0 + 32*st + 8*m + 4*hi);
      }

    // ---- QK^T: 2 s-tiles x 4 e-chunks of 32x32x16 ----
    f32x16 xc[2];
    #pragma unroll
    for (int st = 0; st < 2; ++st) {
      f32x16 cc = z16;
      __builtin_amdgcn_s_setprio(1);
      #pragma unroll
      for (int ec = 0; ec < 4; ++ec) {
        const f16x8 kf = *reinterpret_cast<const f16x8*>(
            &Ks[cur][l31*64 + st*2048 + ((((ec << 2) + (hi << 1)) ^ kxor) << 2)]);
        cc = __builtin_amdgcn_mfma_f32_32x32x16_f16(kf, qf[ec], cc, 0, 0, 0);
      }
      __builtin_amdgcn_s_setprio(0);
      xc[st] = cc;
    }

    // ---- logits ----
    float x[2][16];
    #pragma unroll
    for (int st = 0; st < 2; ++st)
      #pragma unroll
      for (int r = 0; r < 16; ++r)
        x[st][r] = fmaf(mv[st][r>>2][r&3] + lv[st][r>>2][r&3], SCL, xc[st][r]);

    // ---- online softmax: tree max + ONE xor32 shuffle ----
    float mx[8];
    #pragma unroll
    for (int i = 0; i < 8; ++i)
      mx[i] = fmaxf(fmaxf(x[0][i], x[0][i+8]), fmaxf(x[1][i], x[1][i+8]));
    #pragma unroll
    for (int w = 4; w >= 1; w >>= 1)
      #pragma unroll
      for (int i = 0; i < w; ++i) mx[i] = fmaxf(mx[i], mx[i+w]);
    const float tmax = fmaxf(mx[0], __shfl_xor(mx[0], 32));

    if (!__all(tmax <= mrun + 8.f)) {            // defer-max THR=8 (log2)
      const float mnew = fmaxf(mrun, tmax);
      const float rs = __builtin_amdgcn_exp2f(mrun - mnew);
      mrun = mnew; lsum *= rs;
      acc[0] *= rs; acc[1] *= rs;
    }
    float ps = 0.f;
    #pragma unroll
    for (int st = 0; st < 2; ++st)
      #pragma unroll
      for (int i = 0; i < 16; ++i) {
        x[st][i] = __builtin_amdgcn_exp2f(x[st][i] - mrun);
        ps += x[st][i];
      }
    lsum += ps;                                   // cross-lane sum deferred

    // ---- P -> PV B-frags via cvt_pk + permlane32_swap ----
    f16x8 pf[4];
    #pragma unroll
    for (int sc = 0; sc < 4; ++sc) {
      const int st = sc >> 1, b = (sc & 1) * 8;
      const unsigned k0 = pku(x[st][b+0], x[st][b+1]);
      const unsigned k1 = pku(x[st][b+2], x[st][b+3]);
      const unsigned s0_ = pku(x[st][b+4], x[st][b+5]);
      const unsigned s1_ = pku(x[st][b+6], x[st][b+7]);
      auto X = __builtin_amdgcn_permlane32_swap(k0, s0_, false, false);
      auto Y = __builtin_amdgcn_permlane32_swap(k1, s1_, false, false);
      union { unsigned u[4]; f16x8 v; } pu;
      pu.u[0] = X[0]; pu.u[1] = Y[0]; pu.u[2] = X[1]; pu.u[3] = Y[1];
      pf[sc] = pu.v;
    }

    // ---- PV: 2 d-tiles x 4 k-chunks of 32x32x16 ----
    #pragma unroll
    for (int dt = 0; dt < 2; ++dt) {
      __builtin_amdgcn_s_setprio(1);
      #pragma unroll
      for (int sc = 0; sc < 4; ++sc) {
        const int sl0 = ((sc << 2) + (hi << 1)) ^ keyv[dt];
        union { f16x4 h4[2]; f16x8 v; } vu;
        vu.h4[0] = *reinterpret_cast<const f16x4*>(&Vt[cur][vrowb[dt] + (sl0 << 2)]);
        vu.h4[1] = *reinterpret_cast<const f16x4*>(&Vt[cur][vrowb[dt] + ((sl0 ^ 1) << 2)]);
        acc[dt] = __builtin_amdgcn_mfma_f32_32x32x16_f16(vu.v, pf[sc], acc[dt], 0, 0, 0);
      }
      __builtin_amdgcn_s_setprio(0);
    }
  }

  // ---- epilogue ----
  lsum += __shfl_xor(lsum, 32);
  const size_t row = ((size_t)n * kL + qrow) * kH + h;
  if (SPLIT) {
    float* Pp = PO + ((size_t)half * kRows + row) * kD;
    #pragma unroll
    for (int dt = 0; dt < 2; ++dt)
      #pragma unroll
      for (int m = 0; m < 4; ++m) {
        f32x4 o;
        o[0] = acc[dt][4*m+0];
        o[1] = acc[dt][4*m+1];
        o[2] = acc[dt][4*m+2];
        o[3] = acc[dt][4*m+3];
        *reinterpret_cast<f32x4*>(Pp + 32*dt + 8*m + 4*hi) = o;
      }
    if (hi == 0) {
      float* mlp = PML + ((size_t)half * kRows + row) * 2;
      mlp[0] = mrun;
      mlp[1] = lsum;
    }
  } else {
    const float inv = 1.f / lsum;
    float* Op = O + row * kD;
    #pragma unroll
    for (int dt = 0; dt < 2; ++dt)
      #pragma unroll
      for (int m = 0; m < 4; ++m) {
        f32x4 o;
        o[0] = acc[dt][4*m+0] * inv;
        o[1] = acc[dt][4*m+1] * inv;
        o[2] = acc[dt][4*m+2] * inv;
        o[3] = acc[dt][4*m+3] * inv;
        *reinterpret_cast<f32x4*>(Op + 32*dt + 8*m + 4*hi) = o;
      }
  }
}

// Flash split-S combine: O[row][d] = (w0*P0 + w1*P1) / (w0*l0 + w1*l1),
// w_i = exp2(m_i - max(m0,m1)).  48 MB traffic, HBM-bound.
__global__ __launch_bounds__(256)
void combine_kernel(const float* __restrict__ PO, const float* __restrict__ PML,
                    float* __restrict__ O)
{
  const size_t nvec = kOutFl / 4;                 // 1,048,576 float4s
  const size_t stride = (size_t)gridDim.x * blockDim.x;
  for (size_t gid = (size_t)blockIdx.x * blockDim.x + threadIdx.x;
       gid < nvec; gid += stride) {
    const size_t row = gid >> 4;                  // 16 float4s per row
    const float m0 = PML[row*2], l0 = PML[row*2+1];
    const float m1 = PML[kRows*2 + row*2], l1 = PML[kRows*2 + row*2+1];
    const float mm = fmaxf(m0, m1);
    const float w0 = __builtin_amdgcn_exp2f(m0 - mm);
    const float w1 = __builtin_amdgcn_exp2f(m1 - mm);
    const float inv = 1.f / (l0*w0 + l1*w1);
    const f32x4 p0 = reinterpret_cast<const f32x4*>(PO)[gid];
    const f32x4 p1 = reinterpret_cast<const f32x4*>(PO)[nvec + gid];
    f32x4 o;
    #pragma unroll
    for (int r = 0; r < 4; ++r) o[r] = (p0[r]*w0 + p1[r]*w1) * inv;
    reinterpret_cast<f32x4*>(O)[gid] = o;
  }
}

extern "C" void kernel_launch(void* const* d_in, const int* in_sizes, int n_in,
                              void* d_out, int out_size, void* d_ws, size_t ws_size,
                              hipStream_t stream) {
  const float* Q   = (const float*)d_in[0];
  const float* K   = (const float*)d_in[1];
  const float* V   = (const float*)d_in[2];
  const float* M   = (const float*)d_in[3];
  const float* KLN = (const float*)d_in[4];
  float* O = (float*)d_out;

  if (ws_size >= kWsNeed) {
    float* PO  = (float*)d_ws;
    float* PML = PO + kPartFl;
    attn_fwd_kernel<true><<<dim3(kN * kH * (kL/128) * 2), dim3(256), 0, stream>>>(
        Q, K, V, M, KLN, O, PO, PML);
    combine_kernel<<<dim3(2048), dim3(256), 0, stream>>>(PO, PML, O);
  } else {
    attn_fwd_kernel<false><<<dim3(kN * kH * (kL/128)), dim3(256), 0, stream>>>(
        Q, K, V, M, KLN, O, nullptr, nullptr);
  }
}

// Round 10
// 60.088 us; speedup vs baseline: 1.4909x; 1.4909x over previous
//
#include <hip/hip_runtime.h>

typedef _Float16 f16x8  __attribute__((ext_vector_type(8)));
typedef _Float16 f16x4  __attribute__((ext_vector_type(4)));
typedef __fp16   hf2    __attribute__((ext_vector_type(2)));
typedef float    f32x4  __attribute__((ext_vector_type(4)));
typedef float    f32x16 __attribute__((ext_vector_type(16)));

namespace {
constexpr int kN = 4, kL = 1024, kS = 1024, kH = 16, kE = 64, kD = 64;
constexpr int kRowF = kH * kE;     // 1024 floats: s-row stride of K and V
constexpr int KVB = 64;            // keys per LDS chunk
constexpr int NCH = kS / KVB;      // 16 chunks
constexpr float SCL = 0.125f * 1.44269504088896340736f;  // 1/sqrt(E)*log2(e)
}

__device__ __forceinline__ unsigned pku(float a, float b) {
  union { hf2 h; unsigned u; } u;
  u.h = __builtin_amdgcn_cvt_pkrtz(a, b);
  return u.u;
}
__device__ __forceinline__ f16x4 pk4(float a, float b, float c, float d) {
  union { hf2 h2[2]; f16x4 v; } u;
  u.h2[0] = __builtin_amdgcn_cvt_pkrtz(a, b);
  u.h2[1] = __builtin_amdgcn_cvt_pkrtz(c, d);
  return u.v;
}

// Round-6 verified math (fragments, swizzles, swapped scores, T12 permlane
// P-redistribution, defer-max) + LAGGED-PV pipeline:
//   body c: barrier; stage(c+1); QK(c); PV(c-1); softmax(c)->pf
// PV trails one chunk so the MFMA cluster fills the QK->softmax latency gap
// and never sits behind the VALU softmax. V uses a 3-slot rotation
// (chunk j -> Vt[j%3]) so the trailing PV read and the staging write of the
// same body hit disjoint slots with a single barrier per chunk.
__global__ __launch_bounds__(256, 2)
void attn_fwd_kernel(const float* __restrict__ Q, const float* __restrict__ K,
                     const float* __restrict__ V, const float* __restrict__ M,
                     const float* __restrict__ KLN, float* __restrict__ O)
{
  __shared__ _Float16 Ks[2][KVB * 64];
  __shared__ _Float16 Vt[3][kD * 64];

  const int tid  = threadIdx.x;
  const int lane = tid & 63;
  const int wave = tid >> 6;      // 0..3
  const int l31  = lane & 31;     // q within wave-tile; also s/d row in frags
  const int hi   = lane >> 5;
  const int sr   = tid >> 4;      // staging row id 0..15
  const int sc4  = tid & 15;      // staging float4 column

  // XCD swizzle (512 % 8 == 0 -> bijective); all 8 q-blocks of an (n,h)
  // land on one XCD so K/V stay L2-resident there.
  const int swz = ((blockIdx.x & 7) << 6) | (blockIdx.x >> 3);
  const int nh = swz >> 3, qb = swz & 7;
  const int h = nh & (kH - 1), n = nh >> 4;
  const int qrow = qb * 128 + wave * 32 + l31;

  const float* Kp = K + ((size_t)n * kS * kH + h) * kE;
  const float* Vp = V + ((size_t)n * kS * kH + h) * kD;
  const float* Lp = KLN + (size_t)n * kS;
  const float* Mp = M + (size_t)qrow * kS;

  // ---- hoisted Q B-frags (pre-scaled): qf[ec], k = 16*ec + 8*hi + j ----
  f16x8 qf[4];
  {
    const float* Qp = Q + ((size_t)((size_t)n * kL + qrow) * kH + h) * kE;
    #pragma unroll
    for (int ec = 0; ec < 4; ++ec) {
      const f32x4 a = *reinterpret_cast<const f32x4*>(Qp + 16*ec + 8*hi);
      const f32x4 b = *reinterpret_cast<const f32x4*>(Qp + 16*ec + 8*hi + 4);
      union { f16x4 h4[2]; f16x8 v; } u;
      u.h4[0] = pk4(a[0]*SCL, a[1]*SCL, a[2]*SCL, a[3]*SCL);
      u.h4[1] = pk4(b[0]*SCL, b[1]*SCL, b[2]*SCL, b[3]*SCL);
      qf[ec] = u.v;
    }
  }

  // ---- per-thread LDS constants (verified round-6 math) ----
  const int kxor = (l31 & 7) << 1;
  int keyv[2], vrowb[2];
  #pragma unroll
  for (int dt = 0; dt < 2; ++dt) {
    const int d = 32*dt + l31;
    keyv[dt] = ((4*((d>>2)&3) + (d&3)) ^ (d>>2)) & 15;
    vrowb[dt] = d * 64;
  }
  int hwv[4];
  #pragma unroll
  for (int jd = 0; jd < 4; ++jd)
    hwv[jd] = ((4*(sc4 & 3) + jd) ^ sc4) & 15;

  const f32x16 z16 = {0,0,0,0, 0,0,0,0, 0,0,0,0, 0,0,0,0};
  f32x16 acc[2] = {z16, z16};
  float mrun = -1e30f, lsum = 0.f;

  // ---- staging helpers ----
  f32x4 ka[4], va[4];
  auto load_kv = [&](int sbase) {
    #pragma unroll
    for (int i = 0; i < 4; ++i)
      ka[i] = *reinterpret_cast<const f32x4*>(Kp + (size_t)(sbase + 16*i + sr) * kRowF + 4*sc4);
    #pragma unroll
    for (int js = 0; js < 4; ++js)
      va[js] = *reinterpret_cast<const f32x4*>(Vp + (size_t)(sbase + 4*sr + js) * kRowF + 4*sc4);
  };
  auto kv_write = [&](int kbuf, int vslot) {
    #pragma unroll
    for (int i = 0; i < 4; ++i) {
      const int s = 16*i + sr;
      *reinterpret_cast<f16x4*>(&Ks[kbuf][s*64 + ((sc4 ^ ((s & 7) << 1)) << 2)]) =
          pk4(ka[i][0], ka[i][1], ka[i][2], ka[i][3]);
    }
    #pragma unroll
    for (int jd = 0; jd < 4; ++jd) {
      const int d = 4*sc4 + jd;
      *reinterpret_cast<f16x4*>(&Vt[vslot][d*64 + ((sr ^ hwv[jd]) << 2)]) =
          pk4(va[0][jd], va[1][jd], va[2][jd], va[3][jd]);
    }
  };
  f16x8 pf[4] = {};   // P fragments of the previous chunk
  auto pv_step = [&](int vslot) {
    #pragma unroll
    for (int dt = 0; dt < 2; ++dt) {
      #pragma unroll
      for (int sc = 0; sc < 4; ++sc) {
        const int sl0 = ((sc << 2) + (hi << 1)) ^ keyv[dt];
        union { f16x4 h4[2]; f16x8 v; } vu;
        vu.h4[0] = *reinterpret_cast<const f16x4*>(&Vt[vslot][vrowb[dt] + (sl0 << 2)]);
        vu.h4[1] = *reinterpret_cast<const f16x4*>(&Vt[vslot][vrowb[dt] + ((sl0 ^ 1) << 2)]);
        acc[dt] = __builtin_amdgcn_mfma_f32_32x32x16_f16(vu.v, pf[sc], acc[dt], 0, 0, 0);
      }
    }
  };

  // ---- prologue: chunk 0 staged, chunk 1 in flight ----
  load_kv(0);
  kv_write(0, 0);
  load_kv(KVB);

  int sp = 2, scur = 0, sn = 1;   // V slots: (c-1)%3, c%3, (c+1)%3

  for (int c = 0; c < NCH; ++c) {
    const int kcur = c & 1;
    const int s0 = c * KVB;
    __syncthreads();
    if (c + 1 < NCH) kv_write(kcur ^ 1, sn);   // chunk c+1 (loaded body c-1)
    if (c + 2 < NCH) load_kv((c + 2) * KVB);   // written top of body c+1

    // mask / key_lengths prefetch (in flight under QK)
    f32x4 mv[2][4], lv[2][4];
    #pragma unroll
    for (int st = 0; st < 2; ++st)
      #pragma unroll
      for (int m = 0; m < 4; ++m) {
        mv[st][m] = *reinterpret_cast<const f32x4*>(Mp + s0 + 32*st + 8*m + 4*hi);
        lv[st][m] = *reinterpret_cast<const f32x4*>(Lp + s0 + 32*st + 8*m + 4*hi);
      }

    // ---- QK^T(c): 2 s-tiles x 4 e-chunks of 32x32x16 ----
    f32x16 xc[2];
    __builtin_amdgcn_s_setprio(1);
    #pragma unroll
    for (int st = 0; st < 2; ++st) {
      f32x16 cc = z16;
      #pragma unroll
      for (int ec = 0; ec < 4; ++ec) {
        const f16x8 kf = *reinterpret_cast<const f16x8*>(
            &Ks[kcur][l31*64 + st*2048 + ((((ec << 2) + (hi << 1)) ^ kxor) << 2)]);
        cc = __builtin_amdgcn_mfma_f32_32x32x16_f16(kf, qf[ec], cc, 0, 0, 0);
      }
      xc[st] = cc;
    }

    // ---- PV(c-1): trails one chunk; fills the QK->softmax gap ----
    if (c > 0) pv_step(sp);
    __builtin_amdgcn_s_setprio(0);

    // ---- logits(c) ----
    float x[2][16];
    #pragma unroll
    for (int st = 0; st < 2; ++st)
      #pragma unroll
      for (int r = 0; r < 16; ++r)
        x[st][r] = fmaf(mv[st][r>>2][r&3] + lv[st][r>>2][r&3], SCL, xc[st][r]);

    // ---- online softmax(c): tree max + ONE xor32 shuffle ----
    float mx[8];
    #pragma unroll
    for (int i = 0; i < 8; ++i)
      mx[i] = fmaxf(fmaxf(x[0][i], x[0][i+8]), fmaxf(x[1][i], x[1][i+8]));
    #pragma unroll
    for (int w = 4; w >= 1; w >>= 1)
      #pragma unroll
      for (int i = 0; i < w; ++i) mx[i] = fmaxf(mx[i], mx[i+w]);
    const float tmax = fmaxf(mx[0], __shfl_xor(mx[0], 32));

    if (!__all(tmax <= mrun + 8.f)) {          // defer-max THR=8 (log2)
      const float mnew = fmaxf(mrun, tmax);
      const float rs = __builtin_amdgcn_exp2f(mrun - mnew);
      mrun = mnew; lsum *= rs;
      acc[0] *= rs; acc[1] *= rs;              // PV(c-1) already landed
    }
    float ps = 0.f;
    #pragma unroll
    for (int st = 0; st < 2; ++st)
      #pragma unroll
      for (int i = 0; i < 16; ++i) {
        x[st][i] = __builtin_amdgcn_exp2f(x[st][i] - mrun);
        ps += x[st][i];
      }
    lsum += ps;                                 // cross-lane sum deferred

    // ---- pack P(c) -> pf via cvt_pk + permlane32_swap (used next body) ----
    #pragma unroll
    for (int sc = 0; sc < 4; ++sc) {
      const int st = sc >> 1, b = (sc & 1) * 8;
      const unsigned k0 = pku(x[st][b+0], x[st][b+1]);
      const unsigned k1 = pku(x[st][b+2], x[st][b+3]);
      const unsigned s0_ = pku(x[st][b+4], x[st][b+5]);
      const unsigned s1_ = pku(x[st][b+6], x[st][b+7]);
      auto X = __builtin_amdgcn_permlane32_swap(k0, s0_, false, false);
      auto Y = __builtin_amdgcn_permlane32_swap(k1, s1_, false, false);
      union { unsigned u[4]; f16x8 v; } pu;
      pu.u[0] = X[0]; pu.u[1] = Y[0]; pu.u[2] = X[1]; pu.u[3] = Y[1];
      pf[sc] = pu.v;
    }

    // rotate V slots: {p,c,n} -> {c,n,p}
    const int t = sp; sp = scur; scur = sn; sn = t;
  }

  // ---- epilogue: final trailing PV, then normalize + store ----
  pv_step(sp);                                  // sp == (NCH-1)%3 after rotation
  lsum += __shfl_xor(lsum, 32);
  const float inv = 1.f / lsum;
  float* Op = O + (((size_t)n * kL + qrow) * kH + h) * kD;
  #pragma unroll
  for (int dt = 0; dt < 2; ++dt)
    #pragma unroll
    for (int m = 0; m < 4; ++m) {
      f32x4 o;
      o[0] = acc[dt][4*m+0] * inv;
      o[1] = acc[dt][4*m+1] * inv;
      o[2] = acc[dt][4*m+2] * inv;
      o[3] = acc[dt][4*m+3] * inv;
      *reinterpret_cast<f32x4*>(Op + 32*dt + 8*m + 4*hi) = o;
    }
}

extern "C" void kernel_launch(void* const* d_in, const int* in_sizes, int n_in,
                              void* d_out, int out_size, void* d_ws, size_t ws_size,
                              hipStream_t stream) {
  const float* Q   = (const float*)d_in[0];
  const float* K   = (const float*)d_in[1];
  const float* V   = (const float*)d_in[2];
  const float* M   = (const float*)d_in[3];
  const float* KLN = (const float*)d_in[4];
  float* O = (float*)d_out;

  dim3 grid(kN * kH * (kL / 128));  // 512 blocks
  dim3 block(256);                  // 4 waves, 32 queries each
  attn_fwd_kernel<<<grid, block, 0, stream>>>(Q, K, V, M, KLN, O);
}